// Round 7
// baseline (8902.915 us; speedup 1.0000x reference)
//
#include <hip/hip_runtime.h>

// Submanifold sparse conv block, fixed problem size:
// n = 400000 voxels, C = 64, spatial dims B=2, T=21, H=400, W=400.
// All float tensors are fp32 (as declared in the reference).
// lin[i] = ((b*21+t)*400+y)*400+x, sorted ascending by construction.

__global__ void sbb_lin_kernel(const int* idxs, int* lin, int n) {
    int i = blockIdx.x * 256 + threadIdx.x;
    if (i < n) {
        int b = idxs[4 * i];
        int t = idxs[4 * i + 1];
        int y = idxs[4 * i + 2];
        int x = idxs[4 * i + 3];
        lin[i] = ((b * 21 + t) * 400 + y) * 400 + x;
    }
}

// Diagnostic: fill fp32 output with a constant.
__global__ void sbb_fill_kernel(float* p, int nel, float val) {
    int i = blockIdx.x * 256 + threadIdx.x;
    if (i < nel) p[i] = val;
}

// One wave (64 lanes) per voxel, lane = output channel.
// Neighbor lookup: binary search on the sorted lin array (as the reference).
// feats source is fp32 (conv1) or bf16 workspace (conv2), selected by flag.
// Output is fp32 (conv2) or bf16 workspace (conv1), selected by flag.
__global__ void SparseBasicBlock_69965017252009_kernel(
    const float* featsf,            // [n][64] fp32   (used iff feats_bf16 == 0)
    const unsigned short* featsb,   // [n][64] bf16   (used iff feats_bf16 == 1)
    const float* w,                 // [27][64][64] fp32, [k][cin][cout]
    const float* gamma,             // [64] fp32
    const float* beta,              // [64] fp32
    const float* residual,          // [n][64] fp32 (read iff use_residual)
    float* outf,                    // fp32 out (used iff out_bf16 == 0)
    unsigned short* outb,           // bf16 out (used iff out_bf16 == 1)
    const int* lin,                 // [n] sorted linear indices
    const int* idxs,                // [n][4]
    int n,
    int use_residual,
    int feats_bf16,
    int out_bf16)
{
    __shared__ float s1[256];
    __shared__ float s2[256];

    int tid = threadIdx.x;
    int vox = blockIdx.x * 4 + (tid >> 6);
    int co = tid & 63;

    float acc = 0.0f;
    if (vox < n) {
        int t0 = idxs[4 * vox + 1];
        int y0 = idxs[4 * vox + 2];
        int x0 = idxs[4 * vox + 3];
        int mylin = lin[vox];
        for (int dt = -1; dt <= 1; ++dt) {
            for (int dy = -1; dy <= 1; ++dy) {
                for (int dx = -1; dx <= 1; ++dx) {
                    int tt = t0 + dt;
                    int yy = y0 + dy;
                    int xx = x0 + dx;
                    if (tt < 0 || tt >= 21 || yy < 0 || yy >= 400 ||
                        xx < 0 || xx >= 400) continue;
                    int key = mylin + dt * 160000 + dy * 400 + dx;
                    int lo = 0;
                    int hi = n;
                    while (lo < hi) {
                        int mid = (lo + hi) >> 1;
                        if (lin[mid] < key) lo = mid + 1; else hi = mid;
                    }
                    if (lo >= n) continue;
                    if (lin[lo] != key) continue;
                    int kk = (dt + 1) * 9 + (dy + 1) * 3 + (dx + 1);
                    const float* wr = w + kk * 4096 + co;
                    if (feats_bf16) {
                        const unsigned short* fr = featsb + lo * 64;
                        for (int ci = 0; ci < 64; ++ci) {
                            float fa = __uint_as_float(((unsigned)fr[ci]) << 16);
                            acc += fa * wr[ci * 64];
                        }
                    } else {
                        const float* fr = featsf + lo * 64;
                        for (int ci = 0; ci < 64; ++ci) {
                            acc += fr[ci] * wr[ci * 64];
                        }
                    }
                }
            }
        }
    }

    s1[tid] = acc;
    s2[tid] = acc * acc;
    __syncthreads();
    for (int off = 32; off > 0; off >>= 1) {
        if ((tid & 63) < off) {
            s1[tid] += s1[tid + off];
            s2[tid] += s2[tid + off];
        }
        __syncthreads();
    }
    int gb = tid & 192;
    float mean = s1[gb] * 0.015625f;
    float var = s2[gb] * 0.015625f - mean * mean;
    if (var < 0.0f) var = 0.0f;
    float rstd = rsqrtf(var + 1e-5f);

    if (vox < n) {
        float yv = (acc - mean) * rstd * gamma[co] + beta[co];
        int oi = vox * 64 + co;
        if (use_residual) yv += residual[oi];
        if (yv < 0.0f) yv = 0.0f;
        if (out_bf16) {
            unsigned u = __float_as_uint(yv);
            unsigned r = u + 0x7fffu + ((u >> 16) & 1u);
            outb[oi] = (unsigned short)(r >> 16);
        } else {
            outf[oi] = yv;
        }
    }
}

extern "C" void kernel_launch(void* const* d_in, const int* in_sizes, int n_in,
                              void* d_out, int out_size, void* d_ws, size_t ws_size,
                              hipStream_t stream) {
    const float* feats = (const float*)d_in[0];
    const int* idxs = (const int*)d_in[1];
    const float* w1 = (const float*)d_in[2];
    const float* g1 = (const float*)d_in[3];
    const float* b1 = (const float*)d_in[4];
    const float* w2 = (const float*)d_in[5];
    const float* g2 = (const float*)d_in[6];
    const float* b2 = (const float*)d_in[7];
    float* out = (float*)d_out;

    int n = 400000;

    // workspace: lin (1.6 MB int32) then mid (51.2 MB bf16) = 52.8 MB,
    // proven to fit in ws_size (round 6 guard did not trigger).
    size_t need = (size_t)n * 4 + (size_t)n * 128;
    if (ws_size < need) {
        sbb_fill_kernel<<<(n * 64 + 255) / 256, 256, 0, stream>>>(out, n * 64, 1000.0f);
        return;
    }

    int* lin = (int*)d_ws;
    unsigned short* mid = (unsigned short*)((char*)d_ws + (size_t)n * 4);

    sbb_lin_kernel<<<(n + 255) / 256, 256, 0, stream>>>(idxs, lin, n);

    // conv1: fp32 feats in, bf16 mid out, no residual
    SparseBasicBlock_69965017252009_kernel<<<n / 4, 256, 0, stream>>>(
        feats, (const unsigned short*)feats, w1, g1, b1, feats,
        (float*)mid, mid, lin, idxs, n, 0, 0, 1);

    // conv2: bf16 mid in, fp32 out, residual = feats
    SparseBasicBlock_69965017252009_kernel<<<n / 4, 256, 0, stream>>>(
        feats, mid, w2, g2, b2, feats,
        out, (unsigned short*)out, lin, idxs, n, 1, 1, 0);
}